// Round 6
// baseline (571.807 us; speedup 1.0000x reference)
//
#include <hip/hip_runtime.h>
#include <hip/hip_bf16.h>

typedef __hip_bfloat16 bf16;
typedef __attribute__((ext_vector_type(8))) short short8;
typedef __attribute__((ext_vector_type(4))) float f32x4;

#define DIMC 1536
#define NQKV 4608
#define NH   12
#define HD   128
#define NTOK 2304
#define SCTX 256
#define SIN  2048
#define BATCH 2

__device__ __forceinline__ float bf2f(unsigned short u) {
    return __uint_as_float(((unsigned int)u) << 16);
}
__device__ __forceinline__ unsigned short f2bfu(float f) {
    bf16 h = (bf16)f; return *(unsigned short*)&h;
}

// async global->LDS, 16B per lane; LDS dest = wave-uniform base + lane*16
#define GLOAD16(gp, lp) __builtin_amdgcn_global_load_lds(                      \
    (__attribute__((address_space(1))) void*)(gp),                             \
    (__attribute__((address_space(3))) void*)(lp), 16, 0, 0)

// ---------------------------------------------------------------------------
// fp32 -> bf16 elementwise for BOTH input tensors in one launch
// ---------------------------------------------------------------------------
__global__ __launch_bounds__(256) void cvt_both(
    const float* __restrict__ X0, unsigned short* __restrict__ Y0, int n4_0,
    const float* __restrict__ X1, unsigned short* __restrict__ Y1, int n4_1)
{
    int i = blockIdx.x * 256 + threadIdx.x;
    const float* X; unsigned short* Y;
    if (i < n4_0) { X = X0; Y = Y0; }
    else { i -= n4_0; if (i >= n4_1) return; X = X1; Y = Y1; }
    float4 v = ((const float4*)X)[i];
    union { unsigned short u[4]; uint2 p; } o;
    o.u[0] = f2bfu(v.x); o.u[1] = f2bfu(v.y);
    o.u[2] = f2bfu(v.z); o.u[3] = f2bfu(v.w);
    ((uint2*)Y)[i] = o.p;
}

// ---------------------------------------------------------------------------
// Pair of W[K][N] fp32 -> Wt[N][K] bf16 transposes (z = which tensor)
// ---------------------------------------------------------------------------
__global__ __launch_bounds__(256) void transpose_cvt_pair(
    const float* __restrict__ W0, unsigned short* __restrict__ Wt0,
    const float* __restrict__ W1, unsigned short* __restrict__ Wt1,
    int K, int N)
{
    __shared__ float tile[32][33];
    const float* W = blockIdx.z ? W1 : W0;
    unsigned short* Wt = blockIdx.z ? Wt1 : Wt0;
    int n0 = blockIdx.x * 32, k0 = blockIdx.y * 32;
    int tx = threadIdx.x & 31, ty = threadIdx.x >> 5;
    #pragma unroll
    for (int i = 0; i < 4; ++i) {
        int kk = ty + i * 8;
        tile[kk][tx] = W[(size_t)(k0 + kk) * N + n0 + tx];
    }
    __syncthreads();
    #pragma unroll
    for (int i = 0; i < 4; ++i) {
        int nn = ty + i * 8;
        Wt[(size_t)(n0 + nn) * K + k0 + tx] = f2bfu(tile[tx][nn]);
    }
}

// ---------------------------------------------------------------------------
// RoPE table: cos/sin for (p, j), p<NTOK, j<64
// ---------------------------------------------------------------------------
__global__ __launch_bounds__(256) void rope_table(
    float* __restrict__ cost, float* __restrict__ sint)
{
    int idx = blockIdx.x * 256 + threadIdx.x;
    if (idx >= NTOK * 64) return;
    int p = idx >> 6, j = idx & 63;
    float inv_freq = powf(10000.0f, -(float)j * (1.0f / 64.0f));
    float ang = (float)p * inv_freq;
    float sn, cs;
    sincosf(ang, &sn, &cs);
    cost[idx] = cs; sint[idx] = sn;
}

// ---------------------------------------------------------------------------
// bf16 MFMA GEMM (m97 structure), unchanged (verified rounds 3-5).
// ---------------------------------------------------------------------------
__device__ __forceinline__ void storeC(float* p, float v) { *p = v; }
__device__ __forceinline__ void storeC(unsigned short* p, float v) { *p = f2bfu(v); }

template <typename CT>
__global__ __launch_bounds__(256) void gemm_mfma(
    const unsigned short* __restrict__ A, const unsigned short* __restrict__ Wt,
    const float* __restrict__ bias, CT* __restrict__ C,
    int N, int K, int S, int aStr, int aOff, int cStr, int cOff)
{
    __shared__ __align__(16) unsigned short a_lds[128 * 32];
    __shared__ __align__(16) unsigned short b_lds[128 * 32];

    int tid = threadIdx.x;
    int wv = tid >> 6, lane = tid & 63;
    int wm = wv >> 1, wn = wv & 1;
    int quad = lane >> 4, l16 = lane & 15;
    int bm = blockIdx.y * 128, bn = blockIdx.x * 128;

    int m0 = tid >> 2;
    int c  = (tid & 3) ^ ((m0 >> 1) & 3);
    int r0 = bm + m0, r1 = bm + m0 + 64;
    size_t apA0 = ((size_t)((r0 / S) * aStr + aOff + (r0 % S))) * (size_t)K + c * 8;
    size_t apA1 = ((size_t)((r1 / S) * aStr + aOff + (r1 % S))) * (size_t)K + c * 8;
    size_t apB0 = (size_t)(bn + m0) * K + c * 8;
    size_t apB1 = (size_t)(bn + m0 + 64) * K + c * 8;

    unsigned short* ldsA0 = &a_lds[(wv * 64) * 8];
    unsigned short* ldsA1 = &a_lds[(256 + wv * 64) * 8];
    unsigned short* ldsB0 = &b_lds[(wv * 64) * 8];
    unsigned short* ldsB1 = &b_lds[(256 + wv * 64) * 8];

    int gA[4], gB[4];
    #pragma unroll
    for (int mt = 0; mt < 4; ++mt) {
        int m = wm * 64 + mt * 16 + l16;
        gA[mt] = (m * 4 + (quad ^ ((m >> 1) & 3))) * 8;
    }
    #pragma unroll
    for (int nt = 0; nt < 4; ++nt) {
        int n = wn * 64 + nt * 16 + l16;
        gB[nt] = (n * 4 + (quad ^ ((n >> 1) & 3))) * 8;
    }

    f32x4 acc[4][4];
    #pragma unroll
    for (int mt = 0; mt < 4; ++mt)
        #pragma unroll
        for (int nt = 0; nt < 4; ++nt) acc[mt][nt] = (f32x4){0.f, 0.f, 0.f, 0.f};

    for (int k0 = 0; k0 < K; k0 += 32) {
        GLOAD16(A + apA0 + k0, ldsA0);
        GLOAD16(A + apA1 + k0, ldsA1);
        GLOAD16(Wt + apB0 + k0, ldsB0);
        GLOAD16(Wt + apB1 + k0, ldsB1);
        __syncthreads();

        short8 af[4], bfr[4];
        #pragma unroll
        for (int mt = 0; mt < 4; ++mt) af[mt] = *(const short8*)&a_lds[gA[mt]];
        #pragma unroll
        for (int nt = 0; nt < 4; ++nt) bfr[nt] = *(const short8*)&b_lds[gB[nt]];
        #pragma unroll
        for (int mt = 0; mt < 4; ++mt)
            #pragma unroll
            for (int nt = 0; nt < 4; ++nt)
                acc[mt][nt] = __builtin_amdgcn_mfma_f32_16x16x32_bf16(
                    af[mt], bfr[nt], acc[mt][nt], 0, 0, 0);
        __syncthreads();
    }

    float bv[4];
    #pragma unroll
    for (int nt = 0; nt < 4; ++nt) bv[nt] = bias[bn + wn * 64 + nt * 16 + l16];
    #pragma unroll
    for (int mt = 0; mt < 4; ++mt) {
        #pragma unroll
        for (int r = 0; r < 4; ++r) {
            int row = bm + wm * 64 + mt * 16 + quad * 4 + r;
            size_t crow = (size_t)((row / S) * cStr + cOff + (row % S));
            CT* cp = C + crow * (size_t)N + bn + wn * 64 + l16;
            #pragma unroll
            for (int nt = 0; nt < 4; ++nt)
                storeC(cp + nt * 16, acc[mt][nt][r] + bv[nt]);
        }
    }
}

// ---------------------------------------------------------------------------
// RMS norm + scale + RoPE (table-driven); emits bf16 Q/K row-major [b,h,n,d].
// ---------------------------------------------------------------------------
__global__ __launch_bounds__(256) void rms_rope_pack(
    const unsigned short* __restrict__ QKV,
    const float* __restrict__ qs_in, const float* __restrict__ ks_in,
    const float* __restrict__ qs_ctx, const float* __restrict__ ks_ctx,
    const float* __restrict__ cost, const float* __restrict__ sint,
    bf16* __restrict__ Q, bf16* __restrict__ K)
{
    __shared__ float qrow[DIMC];
    __shared__ float krow[DIMC];
    __shared__ float rq[4], rk[4];

    int token = blockIdx.x;
    int b = token / NTOK;
    int p = token % NTOK;
    bool is_ctx = (p < SCTX);
    const float* qs = is_ctx ? qs_ctx : qs_in;
    const float* ks = is_ctx ? ks_ctx : ks_in;

    int t = threadIdx.x;
    const unsigned short* row = QKV + (size_t)token * NQKV;

    float ssq_q = 0.f, ssq_k = 0.f;
    #pragma unroll
    for (int i = 0; i < 6; ++i) {
        int c = t + 256 * i;
        float q = bf2f(row[c]);
        float k = bf2f(row[DIMC + c]);
        qrow[c] = q; krow[c] = k;
        ssq_q += q * q; ssq_k += k * k;
    }
    for (int o = 32; o > 0; o >>= 1) {
        ssq_q += __shfl_down(ssq_q, o);
        ssq_k += __shfl_down(ssq_k, o);
    }
    if ((t & 63) == 0) { rq[t >> 6] = ssq_q; rk[t >> 6] = ssq_k; }
    __syncthreads();
    float sq = rq[0] + rq[1] + rq[2] + rq[3];
    float sk = rk[0] + rk[1] + rk[2] + rk[3];
    float invq = rsqrtf(sq * (1.0f / DIMC) + 1e-6f);
    float invk = rsqrtf(sk * (1.0f / DIMC) + 1e-6f);

    #pragma unroll
    for (int i = 0; i < 6; ++i) {
        int c = t + 256 * i;
        int d = c & 127;
        int j = d & 63;
        float cs = cost[p * 64 + j];
        float sn = sint[p * 64 + j];
        int pc = (d < 64) ? (c + 64) : (c - 64);

        float self_q = qrow[c]  * invq * qs[c];
        float part_q = qrow[pc] * invq * qs[pc];
        float qo = (d < 64) ? (self_q * cs - part_q * sn)
                            : (self_q * cs + part_q * sn);

        float self_k = krow[c]  * invk * ks[c];
        float part_k = krow[pc] * invk * ks[pc];
        float ko = (d < 64) ? (self_k * cs - part_k * sn)
                            : (self_k * cs + part_k * sn);

        int h = c >> 7;
        size_t qi = ((size_t)(b * NH + h) * NTOK + p) * HD + d;
        Q[qi] = (bf16)qo;
        K[qi] = (bf16)ko;
    }
}

// ---------------------------------------------------------------------------
// V transpose: QKV[token][2*DIMC + h*HD + d] -> Vt[bh][d][p]  (bf16)
// ---------------------------------------------------------------------------
__global__ __launch_bounds__(256) void vt_pack(
    const unsigned short* __restrict__ QKV, unsigned short* __restrict__ Vt)
{
    __shared__ unsigned short tileT[128][72];

    int pt = blockIdx.x % (NTOK / 64);
    int bh = blockIdx.x / (NTOK / 64);
    int b = bh / NH, h = bh % NH;
    int p0 = pt * 64;

    int t = threadIdx.x, wv = t >> 6, l = t & 63;

    const unsigned short* src =
        QKV + (size_t)(b * NTOK + p0 + l) * NQKV + 2 * DIMC + h * HD;
    #pragma unroll
    for (int it = 0; it < 4; ++it) {
        int c = it * 4 + wv;
        short8 v = *(const short8*)(src + c * 8);
        const unsigned short* vp = (const unsigned short*)&v;
        #pragma unroll
        for (int i = 0; i < 8; ++i) tileT[c * 8 + i][l] = vp[i];
    }
    __syncthreads();

    int d = t >> 1, jh = (t & 1) * 32;
    unsigned short* dst = Vt + ((size_t)bh * HD + d) * NTOK + p0 + jh;
    #pragma unroll
    for (int k = 0; k < 4; ++k) {
        short8 v = *(const short8*)&tileT[d][jh + k * 8];
        *(short8*)(dst + k * 8) = v;
    }
}

// ---------------------------------------------------------------------------
// Flash attention v3: 64 queries/block (4 waves x 16q), key tile 64.
// Same verified LDS swizzles as round 5; more blocks for occupancy.
// ---------------------------------------------------------------------------
__global__ __launch_bounds__(256, 3) void attn_mfma(
    const unsigned short* __restrict__ Qh,
    const unsigned short* __restrict__ Kh,
    const unsigned short* __restrict__ Vth,
    bf16* __restrict__ O)
{
    __shared__ __align__(16) unsigned short k_lds[64 * 128];   // [j][d] swizzled
    __shared__ __align__(16) unsigned short v_lds[128 * 64];   // [d][j] swizzled
    __shared__ __align__(16) unsigned short p_lds[4][16][72];  // per-wave P[q][j]
    __shared__ float bc[4][16];

    int tid = threadIdx.x;
    int wv = tid >> 6, lane = tid & 63;
    int quad = lane >> 4, l16 = lane & 15;

    int qt = blockIdx.x % (NTOK / 64);
    int bh = blockIdx.x / (NTOK / 64);
    int b = bh / NH, h = bh % NH;
    int qw = qt * 64 + wv * 16;                  // this wave's 16 queries

    const unsigned short* Kbh = Kh + (size_t)bh * NTOK * HD;
    const unsigned short* Vbh = Vth + (size_t)bh * HD * NTOK;

    // Q A-frags (4 dk)
    short8 qf[4];
    {
        const unsigned short* qrow =
            Qh + ((size_t)bh * NTOK + qw + l16) * HD + quad * 8;
        #pragma unroll
        for (int dk = 0; dk < 4; ++dk) qf[dk] = *(const short8*)(qrow + dk * 32);
    }

    float m_r[4], l_r[4];
    f32x4 oac[8];
    #pragma unroll
    for (int r = 0; r < 4; ++r) { m_r[r] = -1e30f; l_r[r] = 0.f; }
    #pragma unroll
    for (int md = 0; md < 8; ++md) oac[md] = (f32x4){0.f, 0.f, 0.f, 0.f};

    const float cscale = 0.08838834764831845f * 1.44269504088896f;

    // staging swizzle indices (verified round 5)
    int jrowK = wv * 4 + (lane >> 4);            // 0..15 (+ it*16)
    int cK = (lane & 15) ^ jrowK;                // global chunk for K
    int dV = wv * 8 + (lane >> 3);               // 0..31 (+ it*32)
    int cV = (lane & 7) ^ (lane >> 3);           // global chunk for Vt

    for (int j0 = 0; j0 < NTOK; j0 += 64) {
        #pragma unroll
        for (int it = 0; it < 4; ++it)
            GLOAD16(Kbh + (size_t)(j0 + it * 16 + jrowK) * HD + cK * 8,
                    &k_lds[(it * 256 + wv * 64) * 8]);
        #pragma unroll
        for (int it = 0; it < 4; ++it)
            GLOAD16(Vbh + (size_t)(it * 32 + dV) * NTOK + j0 + cV * 8,
                    &v_lds[(it * 256 + wv * 64) * 8]);
        __syncthreads();

        // ---- S = Q K^T ----
        f32x4 s[4];
        #pragma unroll
        for (int n = 0; n < 4; ++n) {
            int jl = n * 16 + l16;
            f32x4 a0 = (f32x4){0.f, 0.f, 0.f, 0.f};
            #pragma unroll
            for (int dk = 0; dk < 4; ++dk) {
                short8 kf = *(const short8*)&k_lds[(jl * 16 + ((dk * 4 + quad) ^ l16)) * 8];
                a0 = __builtin_amdgcn_mfma_f32_16x16x32_bf16(qf[dk], kf, a0, 0, 0, 0);
            }
            s[n] = a0;
        }

        // ---- online softmax (row q = quad*4 + r) ----
        float alpha[4], rs[4];
        #pragma unroll
        for (int r = 0; r < 4; ++r) {
            float t = fmaxf(fmaxf(s[0][r], s[1][r]), fmaxf(s[2][r], s[3][r]));
            t = fmaxf(t, __shfl_xor(t, 1));
            t = fmaxf(t, __shfl_xor(t, 2));
            t = fmaxf(t, __shfl_xor(t, 4));
            t = fmaxf(t, __shfl_xor(t, 8));
            float mn = fmaxf(m_r[r], t * cscale);
            alpha[r] = exp2f(m_r[r] - mn);
            m_r[r] = mn;
            rs[r] = 0.f;
        }

        // P = exp2(S*cscale - m): row-major P[q][j] per wave
        #pragma unroll
        for (int n = 0; n < 4; ++n) {
            #pragma unroll
            for (int r = 0; r < 4; ++r) {
                float e = exp2f(s[n][r] * cscale - m_r[r]);
                rs[r] += e;
                p_lds[wv][quad * 4 + r][n * 16 + l16] = f2bfu(e);
            }
        }
        #pragma unroll
        for (int r = 0; r < 4; ++r) {
            float t = rs[r];
            t += __shfl_xor(t, 1);
            t += __shfl_xor(t, 2);
            t += __shfl_xor(t, 4);
            t += __shfl_xor(t, 8);
            l_r[r] = l_r[r] * alpha[r] + t;
        }

        // broadcast alpha to per-lane (q = l16)
        if (l16 == 0) {
            #pragma unroll
            for (int r = 0; r < 4; ++r) bc[wv][quad * 4 + r] = alpha[r];
        }
        float al = bc[wv][l16];
        #pragma unroll
        for (int md = 0; md < 8; ++md) {
            oac[md][0] *= al; oac[md][1] *= al;
            oac[md][2] *= al; oac[md][3] *= al;
        }

        // ---- O^T += V^T P^T ----
        #pragma unroll
        for (int kt = 0; kt < 2; ++kt) {
            short8 pf = *(const short8*)&p_lds[wv][l16][kt * 32 + quad * 8];
            #pragma unroll
            for (int md = 0; md < 8; ++md) {
                int dl = md * 16 + l16;
                short8 vf = *(const short8*)&v_lds[(dl * 8 + ((kt * 4 + quad) ^ (l16 & 7))) * 8];
                oac[md] = __builtin_amdgcn_mfma_f32_16x16x32_bf16(vf, pf, oac[md], 0, 0, 0);
            }
        }
        __syncthreads();
    }

    // ---- epilogue: O^T C-layout -> O[b][p][h*HD+d], 8B packed stores ----
    if (l16 == 0) {
        #pragma unroll
        for (int r = 0; r < 4; ++r) bc[wv][quad * 4 + r] = l_r[r];
    }
    float il = 1.0f / bc[wv][l16];

    int q = qw + l16;
    unsigned short* obase = (unsigned short*)O +
        ((size_t)(b * NTOK) + q) * DIMC + h * HD + quad * 4;
    #pragma unroll
    for (int md = 0; md < 8; ++md) {
        union { unsigned short u[4]; uint2 v; } pk;
        #pragma unroll
        for (int r = 0; r < 4; ++r) pk.u[r] = f2bfu(oac[md][r] * il);
        *(uint2*)(obase + md * 16) = pk.v;
    }
}

// ---------------------------------------------------------------------------
extern "C" void kernel_launch(void* const* d_in, const int* in_sizes, int n_in,
                              void* d_out, int out_size, void* d_ws, size_t ws_size,
                              hipStream_t stream)
{
    const float* input     = (const float*)d_in[0];
    const float* context   = (const float*)d_in[1];
    const float* W_qkv_in  = (const float*)d_in[2];
    const float* b_qkv_in  = (const float*)d_in[3];
    const float* W_qkv_ctx = (const float*)d_in[4];
    const float* b_qkv_ctx = (const float*)d_in[5];
    const float* qs_in     = (const float*)d_in[6];
    const float* ks_in     = (const float*)d_in[7];
    const float* qs_ctx    = (const float*)d_in[8];
    const float* ks_ctx    = (const float*)d_in[9];
    const float* W_out_in  = (const float*)d_in[10];
    const float* b_out_in  = (const float*)d_in[11];
    const float* W_out_ctx = (const float*)d_in[12];
    const float* b_out_ctx = (const float*)d_in[13];
    float* out = (float*)d_out;

    // workspace layout (total 127,401,984 B, same footprint as rounds 3-5)
    char* ws = (char*)d_ws;
    unsigned short* QKVb = (unsigned short*)ws;                    // [4608][4608] bf16
    bf16*           Ob   = (bf16*)ws;                              // [4608][1536] (QKVb dead)
    unsigned short* Qb   = (unsigned short*)(ws + 42467328);       // [2,12,2304,128]
    unsigned short* Kb   = Qb + (size_t)BATCH * NH * NTOK * HD;
    unsigned short* Vtb  = Kb + (size_t)BATCH * NH * NTOK * HD;    // [2,12,128,2304]
    unsigned short* AbIn  = (unsigned short*)(ws + 84934656);      // [4096][1536]
    unsigned short* AbCtx = AbIn + (size_t)BATCH * SIN * DIMC;
    // after QKV gemms, AbIn region is dead -> reuse for rope table, then out-weights
    float* costab = (float*)(ws + 84934656);                       // [2304*64] f32
    float* sintab = costab + NTOK * 64;                            // [2304*64] f32
    unsigned short* WtOutIn  = (unsigned short*)(ws + 84934656);   // overlays (dead by then)
    unsigned short* WtOutCtx = WtOutIn + (size_t)DIMC * DIMC;
    unsigned short* WtQkvIn  = (unsigned short*)(ws + 99090432);   // [4608][1536]
    unsigned short* WtQkvCtx = (unsigned short*)(ws + 113246208);  // [4608][1536]

    // --- convert activations + QKV weights ---
    int n4in = BATCH * SIN * DIMC / 4, n4ctx = BATCH * SCTX * DIMC / 4;
    cvt_both<<<(n4in + n4ctx + 255) / 256, 256, 0, stream>>>(
        input, AbIn, n4in, context, AbCtx, n4ctx);
    transpose_cvt_pair<<<dim3(NQKV / 32, DIMC / 32, 2), 256, 0, stream>>>(
        W_qkv_in, WtQkvIn, W_qkv_ctx, WtQkvCtx, DIMC, NQKV);

    // --- QKV projections (bf16 C, scatter into combined ctx-first order) ---
    gemm_mfma<unsigned short><<<dim3(NQKV / 128, (BATCH * SIN) / 128), 256, 0, stream>>>(
        AbIn, WtQkvIn, b_qkv_in, QKVb, NQKV, DIMC, SIN, SIN, 0, NTOK, SCTX);
    gemm_mfma<unsigned short><<<dim3(NQKV / 128, (BATCH * SCTX) / 128), 256, 0, stream>>>(
        AbCtx, WtQkvCtx, b_qkv_ctx, QKVb, NQKV, DIMC, SCTX, SCTX, 0, NTOK, 0);

    // --- RoPE table (over dead AbIn region), RMS+RoPE (Q,K), V transpose ---
    rope_table<<<(NTOK * 64 + 255) / 256, 256, 0, stream>>>(costab, sintab);
    rms_rope_pack<<<BATCH * NTOK, 256, 0, stream>>>(
        QKVb, qs_in, ks_in, qs_ctx, ks_ctx, costab, sintab, (bf16*)Qb, (bf16*)Kb);
    vt_pack<<<BATCH * NH * (NTOK / 64), 256, 0, stream>>>(QKVb, Vtb);

    // --- attention (bf16 O over dead QKVb region) ---
    attn_mfma<<<BATCH * NH * (NTOK / 64), 256, 0, stream>>>(Qb, Kb, Vtb, Ob);

    // --- out-proj weights (into dead Ab/table region), then projections ---
    transpose_cvt_pair<<<dim3(DIMC / 32, DIMC / 32, 2), 256, 0, stream>>>(
        W_out_in, WtOutIn, W_out_ctx, WtOutCtx, DIMC, DIMC);

    gemm_mfma<float><<<dim3(DIMC / 128, (BATCH * SIN) / 128), 256, 0, stream>>>(
        (const unsigned short*)Ob, WtOutIn, b_out_in, out,
        DIMC, DIMC, SIN, NTOK, SCTX, SIN, 0);
    gemm_mfma<float><<<dim3(DIMC / 128, (BATCH * SCTX) / 128), 256, 0, stream>>>(
        (const unsigned short*)Ob, WtOutCtx, b_out_ctx, out + (size_t)BATCH * SIN * DIMC,
        DIMC, DIMC, SCTX, NTOK, 0, SCTX, 0);
}

// Round 7
// 539.986 us; speedup vs baseline: 1.0589x; 1.0589x over previous
//
#include <hip/hip_runtime.h>
#include <hip/hip_bf16.h>

typedef __hip_bfloat16 bf16;
typedef __attribute__((ext_vector_type(8))) short short8;
typedef __attribute__((ext_vector_type(4))) short s4b;
typedef __attribute__((ext_vector_type(4))) float f32x4;

#define DIMC 1536
#define NQKV 4608
#define NH   12
#define HD   128
#define NTOK 2304
#define SCTX 256
#define SIN  2048
#define BATCH 2
#define KV_SPLIT 2
#define KT_SPLIT (NTOK / 64 / KV_SPLIT)   // 18 key-tiles per split

__device__ __forceinline__ float bf2f(unsigned short u) {
    return __uint_as_float(((unsigned int)u) << 16);
}
__device__ __forceinline__ unsigned short f2bfu(float f) {
    bf16 h = (bf16)f; return *(unsigned short*)&h;
}

#if __has_builtin(__builtin_amdgcn_mfma_f32_16x16x16bf16_1k)
#define HAVE_MFMA16 1
#define MFMA16(a, b, c) __builtin_amdgcn_mfma_f32_16x16x16bf16_1k(a, b, c, 0, 0, 0)
#elif __has_builtin(__builtin_amdgcn_mfma_f32_16x16x16_bf16)
#define HAVE_MFMA16 1
#define MFMA16(a, b, c) __builtin_amdgcn_mfma_f32_16x16x16_bf16(a, b, c, 0, 0, 0)
#else
#define HAVE_MFMA16 0
#endif

// async global->LDS, 16B per lane; LDS dest = wave-uniform base + lane*16
#define GLOAD16(gp, lp) __builtin_amdgcn_global_load_lds(                      \
    (__attribute__((address_space(1))) void*)(gp),                             \
    (__attribute__((address_space(3))) void*)(lp), 16, 0, 0)

// ---------------------------------------------------------------------------
// fp32 -> bf16 elementwise for BOTH input tensors in one launch
// ---------------------------------------------------------------------------
__global__ __launch_bounds__(256) void cvt_both(
    const float* __restrict__ X0, unsigned short* __restrict__ Y0, int n4_0,
    const float* __restrict__ X1, unsigned short* __restrict__ Y1, int n4_1)
{
    int i = blockIdx.x * 256 + threadIdx.x;
    const float* X; unsigned short* Y;
    if (i < n4_0) { X = X0; Y = Y0; }
    else { i -= n4_0; if (i >= n4_1) return; X = X1; Y = Y1; }
    float4 v = ((const float4*)X)[i];
    union { unsigned short u[4]; uint2 p; } o;
    o.u[0] = f2bfu(v.x); o.u[1] = f2bfu(v.y);
    o.u[2] = f2bfu(v.z); o.u[3] = f2bfu(v.w);
    ((uint2*)Y)[i] = o.p;
}

// ---------------------------------------------------------------------------
// Pair of W[K][N] fp32 -> Wt[N][K] bf16 transposes (z = which tensor)
// ---------------------------------------------------------------------------
__global__ __launch_bounds__(256) void transpose_cvt_pair(
    const float* __restrict__ W0, unsigned short* __restrict__ Wt0,
    const float* __restrict__ W1, unsigned short* __restrict__ Wt1,
    int K, int N)
{
    __shared__ float tile[32][33];
    const float* W = blockIdx.z ? W1 : W0;
    unsigned short* Wt = blockIdx.z ? Wt1 : Wt0;
    int n0 = blockIdx.x * 32, k0 = blockIdx.y * 32;
    int tx = threadIdx.x & 31, ty = threadIdx.x >> 5;
    #pragma unroll
    for (int i = 0; i < 4; ++i) {
        int kk = ty + i * 8;
        tile[kk][tx] = W[(size_t)(k0 + kk) * N + n0 + tx];
    }
    __syncthreads();
    #pragma unroll
    for (int i = 0; i < 4; ++i) {
        int nn = ty + i * 8;
        Wt[(size_t)(n0 + nn) * K + k0 + tx] = f2bfu(tile[tx][nn]);
    }
}

// ---------------------------------------------------------------------------
// RoPE table: cos/sin for (p, j), p<NTOK, j<64
// ---------------------------------------------------------------------------
__global__ __launch_bounds__(256) void rope_table(
    float* __restrict__ cost, float* __restrict__ sint)
{
    int idx = blockIdx.x * 256 + threadIdx.x;
    if (idx >= NTOK * 64) return;
    int p = idx >> 6, j = idx & 63;
    float inv_freq = powf(10000.0f, -(float)j * (1.0f / 64.0f));
    float ang = (float)p * inv_freq;
    float sn, cs;
    sincosf(ang, &sn, &cs);
    cost[idx] = cs; sint[idx] = sn;
}

// ---------------------------------------------------------------------------
// bf16 MFMA GEMM (m97 structure), unchanged (verified rounds 3-6).
// ---------------------------------------------------------------------------
__device__ __forceinline__ void storeC(float* p, float v) { *p = v; }
__device__ __forceinline__ void storeC(unsigned short* p, float v) { *p = f2bfu(v); }

template <typename CT>
__global__ __launch_bounds__(256) void gemm_mfma(
    const unsigned short* __restrict__ A, const unsigned short* __restrict__ Wt,
    const float* __restrict__ bias, CT* __restrict__ C,
    int N, int K, int S, int aStr, int aOff, int cStr, int cOff)
{
    __shared__ __align__(16) unsigned short a_lds[128 * 32];
    __shared__ __align__(16) unsigned short b_lds[128 * 32];

    int tid = threadIdx.x;
    int wv = tid >> 6, lane = tid & 63;
    int wm = wv >> 1, wn = wv & 1;
    int quad = lane >> 4, l16 = lane & 15;
    int bm = blockIdx.y * 128, bn = blockIdx.x * 128;

    int m0 = tid >> 2;
    int c  = (tid & 3) ^ ((m0 >> 1) & 3);
    int r0 = bm + m0, r1 = bm + m0 + 64;
    size_t apA0 = ((size_t)((r0 / S) * aStr + aOff + (r0 % S))) * (size_t)K + c * 8;
    size_t apA1 = ((size_t)((r1 / S) * aStr + aOff + (r1 % S))) * (size_t)K + c * 8;
    size_t apB0 = (size_t)(bn + m0) * K + c * 8;
    size_t apB1 = (size_t)(bn + m0 + 64) * K + c * 8;

    unsigned short* ldsA0 = &a_lds[(wv * 64) * 8];
    unsigned short* ldsA1 = &a_lds[(256 + wv * 64) * 8];
    unsigned short* ldsB0 = &b_lds[(wv * 64) * 8];
    unsigned short* ldsB1 = &b_lds[(256 + wv * 64) * 8];

    int gA[4], gB[4];
    #pragma unroll
    for (int mt = 0; mt < 4; ++mt) {
        int m = wm * 64 + mt * 16 + l16;
        gA[mt] = (m * 4 + (quad ^ ((m >> 1) & 3))) * 8;
    }
    #pragma unroll
    for (int nt = 0; nt < 4; ++nt) {
        int n = wn * 64 + nt * 16 + l16;
        gB[nt] = (n * 4 + (quad ^ ((n >> 1) & 3))) * 8;
    }

    f32x4 acc[4][4];
    #pragma unroll
    for (int mt = 0; mt < 4; ++mt)
        #pragma unroll
        for (int nt = 0; nt < 4; ++nt) acc[mt][nt] = (f32x4){0.f, 0.f, 0.f, 0.f};

    for (int k0 = 0; k0 < K; k0 += 32) {
        GLOAD16(A + apA0 + k0, ldsA0);
        GLOAD16(A + apA1 + k0, ldsA1);
        GLOAD16(Wt + apB0 + k0, ldsB0);
        GLOAD16(Wt + apB1 + k0, ldsB1);
        __syncthreads();

        short8 af[4], bfr[4];
        #pragma unroll
        for (int mt = 0; mt < 4; ++mt) af[mt] = *(const short8*)&a_lds[gA[mt]];
        #pragma unroll
        for (int nt = 0; nt < 4; ++nt) bfr[nt] = *(const short8*)&b_lds[gB[nt]];
        #pragma unroll
        for (int mt = 0; mt < 4; ++mt)
            #pragma unroll
            for (int nt = 0; nt < 4; ++nt)
                acc[mt][nt] = __builtin_amdgcn_mfma_f32_16x16x32_bf16(
                    af[mt], bfr[nt], acc[mt][nt], 0, 0, 0);
        __syncthreads();
    }

    float bv[4];
    #pragma unroll
    for (int nt = 0; nt < 4; ++nt) bv[nt] = bias[bn + wn * 64 + nt * 16 + l16];
    #pragma unroll
    for (int mt = 0; mt < 4; ++mt) {
        #pragma unroll
        for (int r = 0; r < 4; ++r) {
            int row = bm + wm * 64 + mt * 16 + quad * 4 + r;
            size_t crow = (size_t)((row / S) * cStr + cOff + (row % S));
            CT* cp = C + crow * (size_t)N + bn + wn * 64 + l16;
            #pragma unroll
            for (int nt = 0; nt < 4; ++nt)
                storeC(cp + nt * 16, acc[mt][nt][r] + bv[nt]);
        }
    }
}

// ---------------------------------------------------------------------------
// RMS norm + scale + RoPE (table-driven); emits bf16 Q/K row-major [b,h,n,d].
// ---------------------------------------------------------------------------
__global__ __launch_bounds__(256) void rms_rope_pack(
    const unsigned short* __restrict__ QKV,
    const float* __restrict__ qs_in, const float* __restrict__ ks_in,
    const float* __restrict__ qs_ctx, const float* __restrict__ ks_ctx,
    const float* __restrict__ cost, const float* __restrict__ sint,
    bf16* __restrict__ Q, bf16* __restrict__ K)
{
    __shared__ float qrow[DIMC];
    __shared__ float krow[DIMC];
    __shared__ float rq[4], rk[4];

    int token = blockIdx.x;
    int b = token / NTOK;
    int p = token % NTOK;
    bool is_ctx = (p < SCTX);
    const float* qs = is_ctx ? qs_ctx : qs_in;
    const float* ks = is_ctx ? ks_ctx : ks_in;

    int t = threadIdx.x;
    const unsigned short* row = QKV + (size_t)token * NQKV;

    float ssq_q = 0.f, ssq_k = 0.f;
    #pragma unroll
    for (int i = 0; i < 6; ++i) {
        int c = t + 256 * i;
        float q = bf2f(row[c]);
        float k = bf2f(row[DIMC + c]);
        qrow[c] = q; krow[c] = k;
        ssq_q += q * q; ssq_k += k * k;
    }
    for (int o = 32; o > 0; o >>= 1) {
        ssq_q += __shfl_down(ssq_q, o);
        ssq_k += __shfl_down(ssq_k, o);
    }
    if ((t & 63) == 0) { rq[t >> 6] = ssq_q; rk[t >> 6] = ssq_k; }
    __syncthreads();
    float sq = rq[0] + rq[1] + rq[2] + rq[3];
    float sk = rk[0] + rk[1] + rk[2] + rk[3];
    float invq = rsqrtf(sq * (1.0f / DIMC) + 1e-6f);
    float invk = rsqrtf(sk * (1.0f / DIMC) + 1e-6f);

    #pragma unroll
    for (int i = 0; i < 6; ++i) {
        int c = t + 256 * i;
        int d = c & 127;
        int j = d & 63;
        float cs = cost[p * 64 + j];
        float sn = sint[p * 64 + j];
        int pc = (d < 64) ? (c + 64) : (c - 64);

        float self_q = qrow[c]  * invq * qs[c];
        float part_q = qrow[pc] * invq * qs[pc];
        float qo = (d < 64) ? (self_q * cs - part_q * sn)
                            : (self_q * cs + part_q * sn);

        float self_k = krow[c]  * invk * ks[c];
        float part_k = krow[pc] * invk * ks[pc];
        float ko = (d < 64) ? (self_k * cs - part_k * sn)
                            : (self_k * cs + part_k * sn);

        int h = c >> 7;
        size_t qi = ((size_t)(b * NH + h) * NTOK + p) * HD + d;
        Q[qi] = (bf16)qo;
        K[qi] = (bf16)ko;
    }
}

// ---------------------------------------------------------------------------
// V transpose: QKV[token][2*DIMC + h*HD + d] -> Vt[bh][d][p]  (bf16)
// ---------------------------------------------------------------------------
__global__ __launch_bounds__(256) void vt_pack(
    const unsigned short* __restrict__ QKV, unsigned short* __restrict__ Vt)
{
    __shared__ unsigned short tileT[128][72];

    int pt = blockIdx.x % (NTOK / 64);
    int bh = blockIdx.x / (NTOK / 64);
    int b = bh / NH, h = bh % NH;
    int p0 = pt * 64;

    int t = threadIdx.x, wv = t >> 6, l = t & 63;

    const unsigned short* src =
        QKV + (size_t)(b * NTOK + p0 + l) * NQKV + 2 * DIMC + h * HD;
    #pragma unroll
    for (int it = 0; it < 4; ++it) {
        int c = it * 4 + wv;
        short8 v = *(const short8*)(src + c * 8);
        const unsigned short* vp = (const unsigned short*)&v;
        #pragma unroll
        for (int i = 0; i < 8; ++i) tileT[c * 8 + i][l] = vp[i];
    }
    __syncthreads();

    int d = t >> 1, jh = (t & 1) * 32;
    unsigned short* dst = Vt + ((size_t)bh * HD + d) * NTOK + p0 + jh;
    #pragma unroll
    for (int k = 0; k < 4; ++k) {
        short8 v = *(const short8*)&tileT[d][jh + k * 8];
        *(short8*)(dst + k * 8) = v;
    }
}

// ---------------------------------------------------------------------------
// Flash attention v4: S^T = K*Q^T formulation (softmax per-lane in q=l16),
// PV via O^T += V^T P^T with 16x16x16 MFMA (P stays in registers).
// 128 queries/block (4 waves x 32q), KV_SPLIT key ranges, partials + combine.
// ---------------------------------------------------------------------------
__global__ __launch_bounds__(256, 3) void attn_mfma(
    const unsigned short* __restrict__ Qh,
    const unsigned short* __restrict__ Kh,
    const unsigned short* __restrict__ Vth,
    unsigned short* __restrict__ PO,   // [split][bh][q][d] bf16, unnormalized
    float2* __restrict__ PL)           // [split][bh*NTOK+q] = (m, l)
{
    __shared__ __align__(16) unsigned short k_lds[64 * 128];   // [j][d] swizzled
    __shared__ __align__(16) unsigned short v_lds[128 * 64];   // [d][j] swizzled
#if !HAVE_MFMA16
    __shared__ __align__(16) unsigned short p_buf[4][2][2][64 * 8];
#endif

    int tid = threadIdx.x;
    int wv = tid >> 6, lane = tid & 63;
    int quad = lane >> 4, l16 = lane & 15;

    int split = blockIdx.x & (KV_SPLIT - 1);
    int rest  = blockIdx.x / KV_SPLIT;
    int qt = rest % (NTOK / 128);
    int bh = rest / (NTOK / 128);
    int qw = qt * 128 + wv * 32;                 // this wave's 32 queries

    const unsigned short* Kbh = Kh + (size_t)bh * NTOK * HD;
    const unsigned short* Vbh = Vth + (size_t)bh * HD * NTOK;

    // Q fragments, used as the B operand of S^T = K*Q^T:
    // B[k=quad*8+j][n=l16] = Q[qw+nsub*16+l16][dk*32+quad*8+j]
    short8 qf[2][4];
    #pragma unroll
    for (int nsub = 0; nsub < 2; ++nsub) {
        const unsigned short* qrow =
            Qh + ((size_t)bh * NTOK + qw + nsub * 16 + l16) * HD + quad * 8;
        #pragma unroll
        for (int dk = 0; dk < 4; ++dk) qf[nsub][dk] = *(const short8*)(qrow + dk * 32);
    }

    float m_r[2] = {-1e30f, -1e30f}, l_r[2] = {0.f, 0.f};
    f32x4 oac[8][2];
    #pragma unroll
    for (int md = 0; md < 8; ++md)
        #pragma unroll
        for (int nsub = 0; nsub < 2; ++nsub) oac[md][nsub] = (f32x4){0.f, 0.f, 0.f, 0.f};

    const float cscale = 0.08838834764831845f * 1.44269504088896f;

    // staging swizzle indices (verified rounds 5-6)
    int jrowK = wv * 4 + (lane >> 4);
    int cK = (lane & 15) ^ jrowK;
    int dV = wv * 8 + (lane >> 3);
    int cV = (lane & 7) ^ (lane >> 3);

    for (int t = 0; t < KT_SPLIT; ++t) {
        int j0 = (split * KT_SPLIT + t) * 64;
        #pragma unroll
        for (int it = 0; it < 4; ++it)
            GLOAD16(Kbh + (size_t)(j0 + it * 16 + jrowK) * HD + cK * 8,
                    &k_lds[(it * 256 + wv * 64) * 8]);
        #pragma unroll
        for (int it = 0; it < 4; ++it)
            GLOAD16(Vbh + (size_t)(it * 32 + dV) * NTOK + j0 + cV * 8,
                    &v_lds[(it * 256 + wv * 64) * 8]);
        __syncthreads();

        // ---- S^T = K Q^T: lane holds S^T[key=msub*16+quad*4+r][q=l16] ----
        f32x4 s[4][2];
        #pragma unroll
        for (int msub = 0; msub < 4; ++msub) {
            f32x4 a0 = (f32x4){0.f, 0.f, 0.f, 0.f};
            f32x4 a1 = (f32x4){0.f, 0.f, 0.f, 0.f};
            #pragma unroll
            for (int dk = 0; dk < 4; ++dk) {
                int jrow = msub * 16 + l16;
                short8 kf = *(const short8*)&k_lds[(jrow * 16 + ((dk * 4 + quad) ^ l16)) * 8];
                a0 = __builtin_amdgcn_mfma_f32_16x16x32_bf16(kf, qf[0][dk], a0, 0, 0, 0);
                a1 = __builtin_amdgcn_mfma_f32_16x16x32_bf16(kf, qf[1][dk], a1, 0, 0, 0);
            }
            s[msub][0] = a0; s[msub][1] = a1;
        }

        // ---- online softmax: q = l16 per-lane; keys spread over (msub, quad, r)
        float alpha[2];
        s4b p4[4][2];
        #pragma unroll
        for (int nsub = 0; nsub < 2; ++nsub) {
            float tmax = s[0][nsub][0];
            #pragma unroll
            for (int msub = 0; msub < 4; ++msub)
                #pragma unroll
                for (int r = 0; r < 4; ++r) tmax = fmaxf(tmax, s[msub][nsub][r]);
            tmax = fmaxf(tmax, __shfl_xor(tmax, 16));
            tmax = fmaxf(tmax, __shfl_xor(tmax, 32));
            float mn = fmaxf(m_r[nsub], tmax * cscale);
            alpha[nsub] = exp2f(m_r[nsub] - mn);
            m_r[nsub] = mn;
            float sum = 0.f;
            #pragma unroll
            for (int msub = 0; msub < 4; ++msub) {
                #pragma unroll
                for (int r = 0; r < 4; ++r) {
                    float e = exp2f(s[msub][nsub][r] * cscale - mn);
                    sum += e;
                    p4[msub][nsub][r] = (short)f2bfu(e);
                }
            }
            sum += __shfl_xor(sum, 16);
            sum += __shfl_xor(sum, 32);
            l_r[nsub] = l_r[nsub] * alpha[nsub] + sum;
        }

        #pragma unroll
        for (int md = 0; md < 8; ++md)
            #pragma unroll
            for (int nsub = 0; nsub < 2; ++nsub) {
                oac[md][nsub][0] *= alpha[nsub]; oac[md][nsub][1] *= alpha[nsub];
                oac[md][nsub][2] *= alpha[nsub]; oac[md][nsub][3] *= alpha[nsub];
            }

#if HAVE_MFMA16
        // ---- O^T += V^T P^T (16x16x16): A = V^T b64 frags, B = P in regs ----
        #pragma unroll
        for (int kstep = 0; kstep < 4; ++kstep) {
            #pragma unroll
            for (int md = 0; md < 8; ++md) {
                int d = md * 16 + l16;
                s4b vA = *(const s4b*)&v_lds[(d * 8 + ((kstep * 2 + (quad >> 1)) ^ (d & 7))) * 8
                                             + (quad & 1) * 4];
                oac[md][0] = MFMA16(vA, p4[kstep][0], oac[md][0]);
                oac[md][1] = MFMA16(vA, p4[kstep][1], oac[md][1]);
            }
        }
#else
        // fallback: pack P^T into B-frag order in LDS, PV via 16x16x32
        #pragma unroll
        for (int nsub = 0; nsub < 2; ++nsub)
            #pragma unroll
            for (int msub = 0; msub < 4; ++msub)
                #pragma unroll
                for (int r = 0; r < 4; ++r) {
                    int o = (msub & 1) * 16 + quad * 4 + r;
                    p_buf[wv][nsub][msub >> 1][((o >> 3) * 16 + l16) * 8 + (o & 7)] =
                        (unsigned short)p4[msub][nsub][r];
                }
        #pragma unroll
        for (int ksub = 0; ksub < 2; ++ksub) {
            short8 pf0 = *(const short8*)&p_buf[wv][0][ksub][lane * 8];
            short8 pf1 = *(const short8*)&p_buf[wv][1][ksub][lane * 8];
            #pragma unroll
            for (int md = 0; md < 8; ++md) {
                int d = md * 16 + l16;
                short8 vf = *(const short8*)&v_lds[(d * 8 + ((ksub * 4 + quad) ^ (d & 7))) * 8];
                oac[md][0] = __builtin_amdgcn_mfma_f32_16x16x32_bf16(vf, pf0, oac[md][0], 0, 0, 0);
                oac[md][1] = __builtin_amdgcn_mfma_f32_16x16x32_bf16(vf, pf1, oac[md][1], 0, 0, 0);
            }
        }
#endif
        __syncthreads();
    }

    // ---- epilogue: store unnormalized partial O (bf16) + (m, l) per q ----
    size_t pobase = ((size_t)split * (BATCH * NH) + bh) * NTOK * HD;
    #pragma unroll
    for (int md = 0; md < 8; ++md)
        #pragma unroll
        for (int nsub = 0; nsub < 2; ++nsub) {
            int q = qw + nsub * 16 + l16;
            union { unsigned short u[4]; uint2 v; } pk;
            #pragma unroll
            for (int r = 0; r < 4; ++r) pk.u[r] = f2bfu(oac[md][nsub][r]);
            *(uint2*)(PO + pobase + (size_t)q * HD + md * 16 + quad * 4) = pk.v;
        }
    if (quad == 0) {
        #pragma unroll
        for (int nsub = 0; nsub < 2; ++nsub) {
            int q = qw + nsub * 16 + l16;
            PL[(size_t)split * (BATCH * NH * NTOK) + (size_t)bh * NTOK + q] =
                make_float2(m_r[nsub], l_r[nsub]);
        }
    }
}

// ---------------------------------------------------------------------------
// Combine KV_SPLIT partials -> Ob[b][p][h*HD+d] bf16
// ---------------------------------------------------------------------------
__global__ __launch_bounds__(256) void attn_combine(
    const unsigned short* __restrict__ PO, const float2* __restrict__ PL,
    unsigned short* __restrict__ Ob)
{
    int idx = blockIdx.x * 256 + threadIdx.x;
    if (idx >= BATCH * NH * NTOK * (HD / 4)) return;
    int qlin = idx >> 5;              // bh*NTOK + q
    int dpos = (idx & 31) * 4;

    float2 ml0 = PL[qlin];
    float2 ml1 = PL[(size_t)(BATCH * NH * NTOK) + qlin];
    float m = fmaxf(ml0.x, ml1.x);
    float w0 = exp2f(ml0.x - m), w1 = exp2f(ml1.x - m);
    float inv = 1.0f / (ml0.y * w0 + ml1.y * w1);

    const size_t stride = (size_t)BATCH * NH * NTOK * HD;
    size_t off = (size_t)qlin * HD + dpos;
    uint2 a = *(const uint2*)(PO + off);
    uint2 b2 = *(const uint2*)(PO + stride + off);
    const unsigned short* au = (const unsigned short*)&a;
    const unsigned short* bu = (const unsigned short*)&b2;
    union { unsigned short u[4]; uint2 v; } pk;
    #pragma unroll
    for (int r = 0; r < 4; ++r)
        pk.u[r] = f2bfu((bf2f(au[r]) * w0 + bf2f(bu[r]) * w1) * inv);

    int bh = qlin / NTOK, q = qlin % NTOK;
    int b = bh / NH, h = bh % NH;
    *(uint2*)(Ob + ((size_t)(b * NTOK) + q) * DIMC + h * HD + dpos) = pk.v;
}

// ---------------------------------------------------------------------------
extern "C" void kernel_launch(void* const* d_in, const int* in_sizes, int n_in,
                              void* d_out, int out_size, void* d_ws, size_t ws_size,
                              hipStream_t stream)
{
    const float* input     = (const float*)d_in[0];
    const float* context   = (const float*)d_in[1];
    const float* W_qkv_in  = (const float*)d_in[2];
    const float* b_qkv_in  = (const float*)d_in[3];
    const float* W_qkv_ctx = (const float*)d_in[4];
    const float* b_qkv_ctx = (const float*)d_in[5];
    const float* qs_in     = (const float*)d_in[6];
    const float* ks_in     = (const float*)d_in[7];
    const float* qs_ctx    = (const float*)d_in[8];
    const float* ks_ctx    = (const float*)d_in[9];
    const float* W_out_in  = (const float*)d_in[10];
    const float* b_out_in  = (const float*)d_in[11];
    const float* W_out_ctx = (const float*)d_in[12];
    const float* b_out_ctx = (const float*)d_in[13];
    float* out = (float*)d_out;

    // workspace layout (total 127,401,984 B, same footprint as rounds 3-6)
    char* ws = (char*)d_ws;
    unsigned short* QKVb = (unsigned short*)ws;                    // [4608][4608] bf16
    unsigned short* Ob   = (unsigned short*)ws;                    // [4608][1536] (QKVb dead)
    unsigned short* PO   = (unsigned short*)(ws + 14155776);       // [2][24][2304][128] bf16
    unsigned short* Qb   = (unsigned short*)(ws + 42467328);       // [2,12,2304,128]
    unsigned short* Kb   = Qb + (size_t)BATCH * NH * NTOK * HD;
    unsigned short* Vtb  = Kb + (size_t)BATCH * NH * NTOK * HD;    // [2,12,128,2304]
    unsigned short* AbIn  = (unsigned short*)(ws + 84934656);      // [4096][1536]
    unsigned short* AbCtx = AbIn + (size_t)BATCH * SIN * DIMC;
    float* costab = (float*)(ws + 84934656);                       // overlays dead AbIn
    float* sintab = costab + NTOK * 64;
    float2* PL    = (float2*)(ws + 86114304);                      // [2][24*2304] float2
    unsigned short* WtOutIn  = (unsigned short*)(ws + 84934656);   // overlays (after combine)
    unsigned short* WtOutCtx = WtOutIn + (size_t)DIMC * DIMC;
    unsigned short* WtQkvIn  = (unsigned short*)(ws + 99090432);   // [4608][1536]
    unsigned short* WtQkvCtx = (unsigned short*)(ws + 113246208);  // [4608][1536]

    // --- convert activations + QKV weights ---
    int n4in = BATCH * SIN * DIMC / 4, n4ctx = BATCH * SCTX * DIMC / 4;
    cvt_both<<<(n4in + n4ctx + 255) / 256, 256, 0, stream>>>(
        input, AbIn, n4in, context, AbCtx, n4ctx);
    transpose_cvt_pair<<<dim3(NQKV / 32, DIMC / 32, 2), 256, 0, stream>>>(
        W_qkv_in, WtQkvIn, W_qkv_ctx, WtQkvCtx, DIMC, NQKV);

    // --- QKV projections (bf16 C, scatter into combined ctx-first order) ---
    gemm_mfma<unsigned short><<<dim3(NQKV / 128, (BATCH * SIN) / 128), 256, 0, stream>>>(
        AbIn, WtQkvIn, b_qkv_in, QKVb, NQKV, DIMC, SIN, SIN, 0, NTOK, SCTX);
    gemm_mfma<unsigned short><<<dim3(NQKV / 128, (BATCH * SCTX) / 128), 256, 0, stream>>>(
        AbCtx, WtQkvCtx, b_qkv_ctx, QKVb, NQKV, DIMC, SCTX, SCTX, 0, NTOK, 0);

    // --- RoPE table (over dead AbIn region), RMS+RoPE (Q,K), V transpose ---
    rope_table<<<(NTOK * 64 + 255) / 256, 256, 0, stream>>>(costab, sintab);
    rms_rope_pack<<<BATCH * NTOK, 256, 0, stream>>>(
        QKVb, qs_in, ks_in, qs_ctx, ks_ctx, costab, sintab, (bf16*)Qb, (bf16*)Kb);
    vt_pack<<<BATCH * NH * (NTOK / 64), 256, 0, stream>>>(QKVb, Vtb);

    // --- attention partials + combine ---
    attn_mfma<<<BATCH * NH * (NTOK / 128) * KV_SPLIT, 256, 0, stream>>>(
        Qb, Kb, Vtb, PO, PL);
    attn_combine<<<(BATCH * NH * NTOK * (HD / 4) + 255) / 256, 256, 0, stream>>>(
        PO, PL, Ob);

    // --- out-proj weights (into dead Ab/table/PL region), then projections ---
    transpose_cvt_pair<<<dim3(DIMC / 32, DIMC / 32, 2), 256, 0, stream>>>(
        W_out_in, WtOutIn, W_out_ctx, WtOutCtx, DIMC, DIMC);

    gemm_mfma<float><<<dim3(DIMC / 128, (BATCH * SIN) / 128), 256, 0, stream>>>(
        Ob, WtOutIn, b_out_in, out,
        DIMC, DIMC, SIN, NTOK, SCTX, SIN, 0);
    gemm_mfma<float><<<dim3(DIMC / 128, (BATCH * SCTX) / 128), 256, 0, stream>>>(
        Ob, WtOutCtx, b_out_ctx, out + (size_t)BATCH * SIN * DIMC,
        DIMC, DIMC, SCTX, NTOK, 0, SCTX, 0);
}